// Round 5
// baseline (11520.689 us; speedup 1.0000x reference)
//
#include <hip/hip_runtime.h>

// SpatialAttentionLSTMDecoder on MI355X (gfx950). B=128,T=32,V=10000,F=H=768,R=49.
// R5: persistent scan kernel (240 blocks, REGULAR launch) with hand-rolled
// device-scope grid barrier (agent-scope atomics). 3 phases/step:
// P1 g1=h@W1.T (split-K2, 240 tiles, BK=128) | P2 per-b attention (jam-4 scores)
// | P3 g2=ctx@Wc.T + fused LSTM (96 tiles, BK=128). fc GEMM: LDS-staged
// float4-store epilogue.

typedef _Float16 f16x8 __attribute__((ext_vector_type(8)));
typedef _Float16 f16x4 __attribute__((ext_vector_type(4)));
typedef float f32x4 __attribute__((ext_vector_type(4)));

#define NB 128
#define NT 32
#define NV 10000
#define NH 768
#define NR 49
#define OUT_ELEMS 40960000  // B*T*V
#define NBLK 240

__device__ __forceinline__ float fast_tanh(float x) {
  x = fminf(9.f, fmaxf(-9.f, x));
  float e = __expf(2.f * x);
  return (e - 1.f) / (e + 1.f);
}
__device__ __forceinline__ float sigm(float x) { return 1.f / (1.f + __expf(-x)); }

__device__ __forceinline__ void gld16(const void* g, void* l) {
  __builtin_amdgcn_global_load_lds((const __attribute__((address_space(1))) void*)g,
                                   (__attribute__((address_space(3))) void*)l, 16, 0, 0);
}

// device-scope grid barrier: cnt zeroed by k_init each launch; gen only compared
// for change (initial value irrelevant, wrap-safe).
__device__ __forceinline__ void gbar(unsigned* cnt, unsigned* gen) {
  __syncthreads();
  if (threadIdx.x == 0) {
    unsigned g = __hip_atomic_load(gen, __ATOMIC_RELAXED, __HIP_MEMORY_SCOPE_AGENT);
    unsigned a = __hip_atomic_fetch_add(cnt, 1u, __ATOMIC_ACQ_REL, __HIP_MEMORY_SCOPE_AGENT);
    if (a == NBLK - 1) {
      __hip_atomic_store(cnt, 0u, __ATOMIC_RELAXED, __HIP_MEMORY_SCOPE_AGENT);
      __hip_atomic_store(gen, g + 1u, __ATOMIC_RELEASE, __HIP_MEMORY_SCOPE_AGENT);
    } else {
      while (__hip_atomic_load(gen, __ATOMIC_ACQUIRE, __HIP_MEMORY_SCOPE_AGENT) == g)
        __builtin_amdgcn_s_sleep(2);
    }
  }
  __syncthreads();
}

// 64x64 f32 tile accumulate, BK=128: A(m0+0..63, :) @ Bt(n0+0..63, :)^T, ld=768.
__device__ __forceinline__ void tile64k128(const _Float16* __restrict__ A,
                                           const _Float16* __restrict__ Bt,
                                           int m0, int n0, int ksteps,
                                           _Float16* sA, _Float16* sB, f32x4 (&acc)[2][2]) {
  const int tid = threadIdx.x;
  const int wid = tid >> 6, lane = tid & 63;
  const int wr = wid >> 1, wc = wid & 1;
  const int lr = lane & 15, lk = (lane >> 4) * 8;
  for (int kt = 0; kt < ksteps; ++kt) {
    const int kbase = kt * 128;
#pragma unroll
    for (int i = 0; i < 4; i++) {
      int idx = tid + i * 256;
      int row = idx >> 4, seg = idx & 15;
      gld16(A + (size_t)(m0 + row) * NH + kbase + seg * 8, sA + idx * 8);
      gld16(Bt + (size_t)(n0 + row) * NH + kbase + seg * 8, sB + idx * 8);
    }
    __syncthreads();
#pragma unroll
    for (int kk = 0; kk < 4; ++kk) {
      f16x8 af[2], bf[2];
#pragma unroll
      for (int m = 0; m < 2; m++)
        af[m] = *(const f16x8*)&sA[(wr * 32 + m * 16 + lr) * 128 + kk * 32 + lk];
#pragma unroll
      for (int n = 0; n < 2; n++)
        bf[n] = *(const f16x8*)&sB[(wc * 32 + n * 16 + lr) * 128 + kk * 32 + lk];
#pragma unroll
      for (int m = 0; m < 2; m++)
#pragma unroll
        for (int n = 0; n < 2; n++)
          acc[m][n] = __builtin_amdgcn_mfma_f32_16x16x32_f16(af[m], bf[n], acc[m][n], 0, 0, 0);
    }
    __syncthreads();
  }
}

// ---------------- persistent scan kernel ----------------
__global__ __launch_bounds__(256, 1) void k_loop(
    const _Float16* __restrict__ fp16, const _Float16* __restrict__ feat16,
    const _Float16* __restrict__ W1, const _Float16* __restrict__ Wc_int,
    const _Float16* __restrict__ Gemb16, const float* __restrict__ bias_int,
    const float* __restrict__ v, float* __restrict__ g1, _Float16* __restrict__ ctx16,
    float* __restrict__ cst, _Float16* __restrict__ h16, _Float16* __restrict__ H_all,
    float* __restrict__ hout, unsigned* __restrict__ cnt, unsigned* __restrict__ gen) {
  __shared__ __attribute__((aligned(16))) char smem[50176];
  _Float16* sA = (_Float16*)smem;            // 16 KB (64x128 f16)
  _Float16* sB = (_Float16*)(smem + 16384);  // 16 KB
  float* sC = (float*)(smem + 32768);        // 64*68*4 = 17408 B
  const int bid = blockIdx.x;
  const int tid = threadIdx.x;
  const int wid = tid >> 6, lane = tid & 63;
  const int wr = wid >> 1, wc = wid & 1;
  const int lr = lane & 15;
  const int rowb = (lane >> 4) * 4;

  for (int t = 0; t < NT; ++t) {
    // ---- P1: g1 partials = h16 @ W1.T (240 tasks: z*120 + mt*60 + nt) ----
    {
      const int z = bid / 120, rem = bid % 120;
      const int m0 = (rem / 60) * 64, n0 = (rem % 60) * 64;
      f32x4 acc[2][2] = {};
      tile64k128(h16 + z * 384, W1 + z * 384, m0, n0, 3, sA, sB, acc);
      float* C = g1 + (size_t)z * NB * 3840;
#pragma unroll
      for (int m = 0; m < 2; m++) {
        int gm = m0 + wr * 32 + m * 16 + rowb;
#pragma unroll
        for (int n = 0; n < 2; n++) {
          int gn = n0 + wc * 32 + n * 16 + lr;
#pragma unroll
          for (int j = 0; j < 4; j++) C[(size_t)(gm + j) * 3840 + gn] = acc[m][n][j];
        }
      }
    }
    gbar(cnt, gen);

    // ---- P2: attention for b = bid (128 tasks) ----
    if (bid < NB) {
      const int b = bid;
      float* hw = (float*)smem;  // 768 f32
      float* sc = hw + NH;       // 64
      float* al = sc + 64;       // 64
      for (int i = tid; i < NH; i += 256)
        hw[i] = g1[(size_t)b * 3840 + i] + g1[(size_t)NB * 3840 + (size_t)b * 3840 + i];
      __syncthreads();
      const _Float16* fpb = fp16 + (size_t)b * NR * NH;
      // scores: jam 4 rows per wave for MLP
      for (int base = 0; base < 13; base += 4) {
        const int rb = wid + base * 4;  // rows rb, rb+4, rb+8, rb+12
        float s[4] = {0.f, 0.f, 0.f, 0.f};
#pragma unroll
        for (int it = 0; it < 3; it++) {
          int hh = it * 256 + lane * 4;
          f32x4 hv = *(f32x4*)&hw[hh];
          f32x4 vv = *(const f32x4*)&v[hh];
#pragma unroll
          for (int j = 0; j < 4; j++) {
            int r = rb + j * 4;
            if (r < NR) {
              f16x4 fv = *(const f16x4*)&fpb[(size_t)r * NH + hh];
#pragma unroll
              for (int q = 0; q < 4; q++) s[j] += fast_tanh((float)fv[q] + hv[q]) * vv[q];
            }
          }
        }
#pragma unroll
        for (int j = 0; j < 4; j++) {
          int r = rb + j * 4;
          if (r < NR) {
            float ss = s[j];
#pragma unroll
            for (int off = 32; off; off >>= 1) ss += __shfl_down(ss, off);
            if (lane == 0) sc[r] = ss;
          }
        }
      }
      __syncthreads();
      if (tid < 64) {
        float s = (tid < NR) ? sc[tid] : -1e30f;
        float m = s;
#pragma unroll
        for (int off = 32; off; off >>= 1) m = fmaxf(m, __shfl_xor(m, off));
        float e = (tid < NR) ? __expf(s - m) : 0.f;
        float su = e;
#pragma unroll
        for (int off = 32; off; off >>= 1) su += __shfl_xor(su, off);
        al[tid] = e / su;
      }
      __syncthreads();
#pragma unroll
      for (int j = 0; j < 3; j++) {
        int f = tid + j * 256;
        const _Float16* fb = feat16 + (size_t)b * NR * NH + f;
        float acc = 0.f;
#pragma unroll
        for (int r = 0; r < NR; r++) acc += al[r] * (float)fb[(size_t)r * NH];
        ctx16[(size_t)b * NH + f] = (_Float16)acc;
      }
    }
    gbar(cnt, gen);

    // ---- P3: g2 = ctx @ Wc_int.T + fused LSTM (96 tasks) ----
    if (bid < 96) {
      const int m0 = (bid / 48) * 64, n0 = (bid % 48) * 64;
      f32x4 acc[2][2] = {};
      tile64k128(ctx16, Wc_int, m0, n0, 6, sA, sB, acc);
#pragma unroll
      for (int m = 0; m < 2; m++) {
        int bl = wr * 32 + m * 16 + rowb;
#pragma unroll
        for (int n = 0; n < 2; n++) {
          int jl = wc * 32 + n * 16 + lr;
#pragma unroll
          for (int j = 0; j < 4; j++) sC[(bl + j) * 68 + jl] = acc[m][n][j];
        }
      }
      __syncthreads();
      const _Float16* ge_t = Gemb16 + (size_t)t * NB * 3072;
      const int b_l = tid & 63;
      const int b_g = m0 + b_l;
#pragma unroll
      for (int i = 0; i < 4; i++) {
        int hh_l = (tid >> 6) * 4 + i;
        int hh_g = (n0 >> 2) + hh_l;
        f32x4 g = *(const f32x4*)&sC[b_l * 68 + 4 * hh_l];
        f32x4 p0 = *(const f32x4*)&g1[(size_t)b_g * 3840 + 768 + 4 * hh_g];
        f32x4 p1 = *(const f32x4*)&g1[(size_t)NB * 3840 + (size_t)b_g * 3840 + 768 + 4 * hh_g];
        f16x4 ge = *(const f16x4*)&ge_t[(size_t)b_g * 3072 + 4 * hh_g];
        f32x4 bi = *(const f32x4*)&bias_int[4 * hh_g];
        float gi = g[0] + p0[0] + p1[0] + (float)ge[0] + bi[0];
        float gf = g[1] + p0[1] + p1[1] + (float)ge[1] + bi[1];
        float gg = g[2] + p0[2] + p1[2] + (float)ge[2] + bi[2];
        float go = g[3] + p0[3] + p1[3] + (float)ge[3] + bi[3];
        float cn = sigm(gf) * cst[b_g * NH + hh_g] + sigm(gi) * fast_tanh(gg);
        float hn = sigm(go) * fast_tanh(cn);
        cst[b_g * NH + hh_g] = cn;
        h16[(size_t)b_g * NH + hh_g] = (_Float16)hn;
        H_all[(size_t)t * NB * NH + (size_t)b_g * NH + hh_g] = (_Float16)hn;
        if (t == NT - 1) hout[(size_t)b_g * NH + hh_g] = hn;
      }
    }
    gbar(cnt, gen);
  }
}

// ---------------- batch GEMM (phase A / fc) ----------------
// EPI 2: fc epilogue (LDS-staged, float4 stores, (b,t) remap, bias, n<N guard).
// EPI 3: f16 out + bias.  EPI 4: f16 out plain.
template <int BM, int BN, int EPI>
__global__ __launch_bounds__(256) void gemm_f16(
    const _Float16* __restrict__ A, int lda,
    const _Float16* __restrict__ Bt, int ldb,
    void* __restrict__ Cv, const float* __restrict__ bias,
    int M, int N, int ksteps) {
  constexpr int BK = 64;
  __shared__ __attribute__((aligned(16))) _Float16 sA[BM * BK];
  __shared__ __attribute__((aligned(16))) _Float16 sB[BN * BK];
  const int tid = threadIdx.x;
  const int m0 = blockIdx.x * BM, n0 = blockIdx.y * BN;

  constexpr int WM = BM / 2, WN = BN / 2;
  constexpr int MF = WM / 16, NF = WN / 16;
  const int wid = tid >> 6, lane = tid & 63;
  const int wr = wid >> 1, wc = wid & 1;
  const int lr = lane & 15;
  const int lk = (lane >> 4) * 8;

  f32x4 acc[MF][NF] = {};

  for (int kt = 0; kt < ksteps; ++kt) {
    const int kbase = kt * BK;
#pragma unroll
    for (int i = 0; i < BM / 32; i++) {
      int idx = tid + i * 256;
      int row = idx >> 3, seg = idx & 7;
      gld16(A + (size_t)(m0 + row) * lda + kbase + seg * 8, sA + idx * 8);
    }
#pragma unroll
    for (int i = 0; i < BN / 32; i++) {
      int idx = tid + i * 256;
      int row = idx >> 3, seg = idx & 7;
      int gr = n0 + row;
      if (gr >= N) gr = N - 1;  // only possible for EPI==2 (N=10000)
      gld16(Bt + (size_t)gr * ldb + kbase + seg * 8, sB + idx * 8);
    }
    __syncthreads();
#pragma unroll
    for (int kk = 0; kk < 2; ++kk) {
      f16x8 af[MF], bf[NF];
#pragma unroll
      for (int m = 0; m < MF; m++)
        af[m] = *(const f16x8*)&sA[(wr * WM + m * 16 + lr) * BK + kk * 32 + lk];
#pragma unroll
      for (int n = 0; n < NF; n++)
        bf[n] = *(const f16x8*)&sB[(wc * WN + n * 16 + lr) * BK + kk * 32 + lk];
#pragma unroll
      for (int m = 0; m < MF; m++)
#pragma unroll
        for (int n = 0; n < NF; n++)
          acc[m][n] = __builtin_amdgcn_mfma_f32_16x16x32_f16(af[m], bf[n], acc[m][n], 0, 0, 0);
    }
    __syncthreads();
  }

  const int rowb = (lane >> 4) * 4;
  if (EPI == 2) {
    // LDS-staged epilogue: two 64-row halves, float4 coalesced stores.
    float* sC = (float*)sA;  // 64*128*4 = 32 KB, aliases sA+sB
#pragma unroll
    for (int h = 0; h < 2; h++) {
      if (wr == h) {
#pragma unroll
        for (int m = 0; m < MF; m++)
#pragma unroll
          for (int n = 0; n < NF; n++)
#pragma unroll
            for (int j = 0; j < 4; j++)
              sC[(m * 16 + rowb + j) * 128 + wc * 64 + n * 16 + lr] = acc[m][n][j];
      }
      __syncthreads();
#pragma unroll
      for (int i = 0; i < 8; i++) {
        int lrow = (tid >> 5) + i * 8;
        int col = (tid & 31) * 4;
        int gn = n0 + col;
        if (gn < N) {
          int r = m0 + h * 64 + lrow;
          int tt = r >> 7, b = r & 127;
          f32x4 val = *(f32x4*)&sC[lrow * 128 + col];
          f32x4 bb = *(const f32x4*)&bias[gn];
          val += bb;
          *(f32x4*)&((float*)Cv)[((size_t)(b * NT + tt)) * NV + gn] = val;
        }
      }
      __syncthreads();
    }
    return;
  }
#pragma unroll
  for (int m = 0; m < MF; m++) {
    int gm = m0 + wr * WM + m * 16 + rowb;
#pragma unroll
    for (int n = 0; n < NF; n++) {
      int gn = n0 + wc * WN + n * 16 + lr;
#pragma unroll
      for (int j = 0; j < 4; j++) {
        int r = gm + j;
        if (EPI == 3) {
          ((_Float16*)Cv)[(size_t)r * N + gn] = (_Float16)(acc[m][n][j] + bias[gn]);
        } else {
          ((_Float16*)Cv)[(size_t)r * N + gn] = (_Float16)acc[m][n][j];
        }
      }
    }
  }
}

// ---------------- prep kernels ----------------
__global__ void k_f32_to_f16(const float* __restrict__ src, _Float16* __restrict__ dst, int n) {
  int i = blockIdx.x * 256 + threadIdx.x;
  if (i < n) dst[i] = (_Float16)src[i];
}

// interleaved gate weights: j' = 4*hh + gate  (src row = gate*768 + hh)
__global__ void k_wint(const float* __restrict__ W_ih, const float* __restrict__ W_hh,
                       _Float16* __restrict__ We_int, _Float16* __restrict__ Wc_int,
                       _Float16* __restrict__ W1) {
  int jp = blockIdx.x;  // 0..3071
  int k = blockIdx.y * 256 + threadIdx.x;
  int src = (jp & 3) * NH + (jp >> 2);
  We_int[(size_t)jp * NH + k] = (_Float16)W_ih[(size_t)src * 1536 + k];
  Wc_int[(size_t)jp * NH + k] = (_Float16)W_ih[(size_t)src * 1536 + 768 + k];
  W1[(size_t)(768 + jp) * NH + k] = (_Float16)W_hh[(size_t)src * NH + k];
}

__global__ void k_wh(const float* __restrict__ attn_W, _Float16* __restrict__ W1) {
  int j = blockIdx.x;
  int k = blockIdx.y * 256 + threadIdx.x;
  W1[(size_t)j * NH + k] = (_Float16)attn_W[(size_t)j * 1536 + 768 + k];
}

__global__ void k_bias(const float* __restrict__ b_ih, const float* __restrict__ b_hh,
                       float* __restrict__ bias_int) {
  int jp = blockIdx.x * 256 + threadIdx.x;  // 3072
  int src = (jp & 3) * NH + (jp >> 2);
  bias_int[jp] = b_ih[src] + b_hh[src];
}

__global__ void k_emb2(const int* __restrict__ captions, const float* __restrict__ emb_W,
                       _Float16* __restrict__ emb16) {
  int row = blockIdx.x;  // t*128+b
  int k = blockIdx.y * 256 + threadIdx.x;
  int t = row >> 7, b = row & 127;
  int tok = captions[b * NT + t];
  emb16[(size_t)row * NH + k] = (_Float16)emb_W[(size_t)tok * NH + k];
}

__global__ void k_init(const float* __restrict__ features, float* __restrict__ c,
                       _Float16* __restrict__ h16, unsigned* __restrict__ cnt) {
  int b = blockIdx.x;
  int f = blockIdx.y * 256 + threadIdx.x;
  if (b == 0 && f == 0) *cnt = 0u;  // barrier counter init (poison-proof)
  float s = 0.f;
#pragma unroll 7
  for (int r = 0; r < NR; r++) s += features[((size_t)(b * NR + r)) * NH + f];
  float h0 = tanhf(s * (1.f / 49.f));
  c[b * NH + f] = 0.f;
  h16[(size_t)b * NH + f] = (_Float16)h0;
}

__global__ void k_tail(const float* __restrict__ h, const float* __restrict__ c,
                       float* __restrict__ out) {
  int i = blockIdx.x * 256 + threadIdx.x;  // 98304
  out[OUT_ELEMS + i] = h[i];
  out[OUT_ELEMS + NB * NH + i] = c[i];
}

// ---------------- host ----------------
extern "C" void kernel_launch(void* const* d_in, const int* in_sizes, int n_in,
                              void* d_out, int out_size, void* d_ws, size_t ws_size,
                              hipStream_t stream) {
  const float* features = (const float*)d_in[0];
  const int* captions = (const int*)d_in[1];
  const float* emb_W = (const float*)d_in[2];
  const float* attn_W = (const float*)d_in[3];
  const float* attn_b = (const float*)d_in[4];
  const float* attnv_W = (const float*)d_in[5];
  // d_in[6] attnv_b: constant shift, cancels in softmax
  const float* W_ih = (const float*)d_in[7];
  const float* W_hh = (const float*)d_in[8];
  const float* b_ih = (const float*)d_in[9];
  const float* b_hh = (const float*)d_in[10];
  const float* fc_W = (const float*)d_in[11];
  const float* fc_b = (const float*)d_in[12];
  float* out = (float*)d_out;

  char* p = (char*)d_ws;
  _Float16* Gemb16 = (_Float16*)p;  p += 25165824;  // (4096,3072) interleaved; aliased by fcW16
  _Float16* fcW16 = Gemb16;                         // (10000,768), reuse after scan
  _Float16* emb16 = (_Float16*)p;   p += 6291456;   // (4096,768): row t*128+b
  _Float16* feat16 = (_Float16*)p;  p += 9633792;   // (6272,768)
  _Float16* fp16 = (_Float16*)p;    p += 9633792;   // feat_proj + attn_b (6272,768)
  _Float16* attnW16 = (_Float16*)p; p += 2359296;   // (768,1536)
  _Float16* W1 = (_Float16*)p;      p += 5898240;   // (3840,768): [Wh ; Whh_int]
  _Float16* We_int = (_Float16*)p;  p += 4718592;   // (3072,768)
  _Float16* Wc_int = (_Float16*)p;  p += 4718592;   // (3072,768)
  _Float16* H_all = (_Float16*)p;   p += 6291456;   // (4096,768): row t*128+b
  float* g1 = (float*)p;            p += 3932160;   // 2 x (128,3840)
  float* bias_int = (float*)p;      p += 12288;     // (3072,)
  _Float16* ctx16 = (_Float16*)p;   p += 196608;    // (128,768)
  _Float16* h16 = (_Float16*)p;     p += 196608;    // (128,768)
  float* hbuf = (float*)p;          p += 393216;
  float* cbuf = (float*)p;          p += 393216;
  unsigned* barv = (unsigned*)p;    p += 256;       // [0]=cnt, [1]=gen

  // ---- phase A ----
  k_f32_to_f16<<<dim3(18816), 256, 0, stream>>>(features, feat16, 4816896);
  k_f32_to_f16<<<dim3(4608), 256, 0, stream>>>(attn_W, attnW16, 1179648);
  k_wint<<<dim3(3072, 3), 256, 0, stream>>>(W_ih, W_hh, We_int, Wc_int, W1);
  k_wh<<<dim3(768, 3), 256, 0, stream>>>(attn_W, W1);
  k_bias<<<dim3(12), 256, 0, stream>>>(b_ih, b_hh, bias_int);
  k_emb2<<<dim3(4096, 3), 256, 0, stream>>>(captions, emb_W, emb16);
  k_init<<<dim3(128, 3), 256, 0, stream>>>(features, cbuf, h16, barv);
  // fp16 = features @ Wf.T + attn_b   (6272x768, K=768)
  gemm_f16<128, 128, 3><<<dim3(49, 6), 256, 0, stream>>>(
      feat16, 768, attnW16, 1536, fp16, attn_b, 6272, 768, 12);
  // Gemb = emb @ We_int.T  (4096x3072, K=768), f16, interleaved cols
  gemm_f16<128, 128, 4><<<dim3(32, 24), 256, 0, stream>>>(
      emb16, 768, We_int, 768, Gemb16, nullptr, 4096, 3072, 12);

  // ---- persistent scan: regular launch, manual grid barrier ----
  k_loop<<<dim3(NBLK), 256, 0, stream>>>(fp16, feat16, W1, Wc_int, Gemb16, bias_int,
                                         attnv_W, g1, ctx16, cbuf, h16, H_all, hbuf,
                                         barv, barv + 1);

  // ---- fc (fcW16 aliases Gemb16, safe after scan in stream order) ----
  k_f32_to_f16<<<dim3(30000), 256, 0, stream>>>(fc_W, fcW16, 7680000);
  gemm_f16<128, 128, 2><<<dim3(32, 79), 256, 0, stream>>>(
      H_all, 768, fcW16, 768, out, fc_b, 4096, 10000, 12);
  k_tail<<<dim3(384), 256, 0, stream>>>(hbuf, cbuf, out);
}

// Round 6
// 1746.874 us; speedup vs baseline: 6.5950x; 6.5950x over previous
//
#include <hip/hip_runtime.h>

// SpatialAttentionLSTMDecoder on MI355X (gfx950). B=128,T=32,V=10000,F=H=768,R=49.
// R6: 3 launches/step, all wide+shallow: g1 GEMM (BK=128, 240 blk) ->
// fused attention (jam-4 scores, 128 blk) -> g2 GEMM+LSTM (BN=32, BK=128, 192 blk).
// fc GEMM with LDS-staged float4-store epilogue. Persistent/grid-barrier path
// abandoned (R5: 118 us/barrier, atomic serialization).

typedef _Float16 f16x8 __attribute__((ext_vector_type(8)));
typedef _Float16 f16x4 __attribute__((ext_vector_type(4)));
typedef float f32x4 __attribute__((ext_vector_type(4)));

#define NB 128
#define NT 32
#define NV 10000
#define NH 768
#define NR 49
#define OUT_ELEMS 40960000  // B*T*V

__device__ __forceinline__ float fast_tanh(float x) {
  x = fminf(9.f, fmaxf(-9.f, x));
  float e = __expf(2.f * x);
  return (e - 1.f) / (e + 1.f);
}
__device__ __forceinline__ float sigm(float x) { return 1.f / (1.f + __expf(-x)); }

__device__ __forceinline__ void gld16(const void* g, void* l) {
  __builtin_amdgcn_global_load_lds((const __attribute__((address_space(1))) void*)g,
                                   (__attribute__((address_space(3))) void*)l, 16, 0, 0);
}

// ---------------- generic f16 MFMA GEMM (16x16x32) ----------------
// C[m][n] = sum_k A[m][k]*Bt[n][k]. A: MxK lda, Bt: NxK ldb (both f16 row-major).
// EPI 1: f32 partials, C += z*M*N.
// EPI 2: fc epilogue: LDS-staged float4 stores, (b,t) remap, +bias, n<N guard.
// EPI 3: f16 out + bias.  EPI 4: f16 out plain.
template <int BM, int BN, int EPI, int BK>
__global__ __launch_bounds__(256) void gemm_f16(
    const _Float16* __restrict__ A, int lda,
    const _Float16* __restrict__ Bt, int ldb,
    void* __restrict__ Cv, const float* __restrict__ bias,
    int M, int N, int ksteps, int ksplit) {
  constexpr int SEG = BK / 8;  // 16B segments per row
  __shared__ __attribute__((aligned(16))) _Float16 sA[BM * BK];
  __shared__ __attribute__((aligned(16))) _Float16 sB[BN * BK];
  const int tid = threadIdx.x;
  const int m0 = blockIdx.x * BM, n0 = blockIdx.y * BN;
  const int z = blockIdx.z;
  A += (size_t)z * ksplit;
  Bt += (size_t)z * ksplit;

  constexpr int WM = BM / 2, WN = BN / 2;
  constexpr int MF = WM / 16, NF = WN / 16;
  const int wid = tid >> 6, lane = tid & 63;
  const int wr = wid >> 1, wc = wid & 1;
  const int lr = lane & 15;
  const int lk = (lane >> 4) * 8;

  f32x4 acc[MF][NF] = {};

  for (int kt = 0; kt < ksteps; ++kt) {
    const int kbase = kt * BK;
#pragma unroll
    for (int i = 0; i < BM * BK / 2048; i++) {
      int idx = tid + i * 256;
      int row = idx / SEG, seg = idx % SEG;
      gld16(A + (size_t)(m0 + row) * lda + kbase + seg * 8, sA + idx * 8);
    }
#pragma unroll
    for (int i = 0; i < BN * BK / 2048; i++) {
      int idx = tid + i * 256;
      int row = idx / SEG, seg = idx % SEG;
      int gr = n0 + row;
      if (gr >= N) gr = N - 1;  // only possible for EPI==2 (N=10000)
      gld16(Bt + (size_t)gr * ldb + kbase + seg * 8, sB + idx * 8);
    }
    __syncthreads();
#pragma unroll
    for (int kk = 0; kk < BK / 32; ++kk) {
      f16x8 af[MF], bf[NF];
#pragma unroll
      for (int m = 0; m < MF; m++)
        af[m] = *(const f16x8*)&sA[(wr * WM + m * 16 + lr) * BK + kk * 32 + lk];
#pragma unroll
      for (int n = 0; n < NF; n++)
        bf[n] = *(const f16x8*)&sB[(wc * WN + n * 16 + lr) * BK + kk * 32 + lk];
#pragma unroll
      for (int m = 0; m < MF; m++)
#pragma unroll
        for (int n = 0; n < NF; n++)
          acc[m][n] = __builtin_amdgcn_mfma_f32_16x16x32_f16(af[m], bf[n], acc[m][n], 0, 0, 0);
    }
    __syncthreads();
  }

  const int rowb = (lane >> 4) * 4;
  if (EPI == 2) {
    // LDS-staged epilogue: two 64-row halves, float4 coalesced stores.
    float* sC = (float*)sA;  // 64*128*4 = 32 KB, aliases sA+sB
#pragma unroll
    for (int h = 0; h < 2; h++) {
      if (wr == h) {
#pragma unroll
        for (int m = 0; m < MF; m++)
#pragma unroll
          for (int n = 0; n < NF; n++)
#pragma unroll
            for (int j = 0; j < 4; j++)
              sC[(m * 16 + rowb + j) * 128 + wc * 64 + n * 16 + lr] = acc[m][n][j];
      }
      __syncthreads();
#pragma unroll
      for (int i = 0; i < 8; i++) {
        int lrow = (tid >> 5) + i * 8;
        int col = (tid & 31) * 4;
        int gn = n0 + col;
        if (gn < N) {
          int r = m0 + h * 64 + lrow;
          int tt = r >> 7, b = r & 127;
          f32x4 val = *(f32x4*)&sC[lrow * 128 + col];
          f32x4 bb = *(const f32x4*)&bias[gn];
          val += bb;
          *(f32x4*)&((float*)Cv)[((size_t)(b * NT + tt)) * NV + gn] = val;
        }
      }
      __syncthreads();
    }
    return;
  }
#pragma unroll
  for (int m = 0; m < MF; m++) {
    int gm = m0 + wr * WM + m * 16 + rowb;
#pragma unroll
    for (int n = 0; n < NF; n++) {
      int gn = n0 + wc * WN + n * 16 + lr;
#pragma unroll
      for (int j = 0; j < 4; j++) {
        int r = gm + j;
        if (EPI == 1) {
          float* C = (float*)Cv + (size_t)z * M * N;
          C[(size_t)r * N + gn] = acc[m][n][j];
        } else if (EPI == 3) {
          ((_Float16*)Cv)[(size_t)r * N + gn] = (_Float16)(acc[m][n][j] + bias[gn]);
        } else {
          ((_Float16*)Cv)[(size_t)r * N + gn] = (_Float16)acc[m][n][j];
        }
      }
    }
  }
}

// ---------------- fused attention: jam-4 scores + softmax + ctx (128 blocks) ----------------
__global__ __launch_bounds__(256) void k_attn(
    const _Float16* __restrict__ fp, const float* __restrict__ g1,
    const float* __restrict__ v, const _Float16* __restrict__ feat16,
    _Float16* __restrict__ ctx16) {
  __shared__ float hw[NH], sc[64], al[64];
  const int b = blockIdx.x, tid = threadIdx.x;
  const int wid = tid >> 6, lane = tid & 63;
  for (int i = tid; i < NH; i += 256)
    hw[i] = g1[(size_t)b * 3840 + i] + g1[(size_t)NB * 3840 + (size_t)b * 3840 + i];
  __syncthreads();
  const _Float16* fpb = fp + (size_t)b * NR * NH;
  // scores: jam 4 rows per wave
  for (int base = 0; base < 13; base += 4) {
    const int rb = wid + base * 4;  // rows rb, rb+4, rb+8, rb+12
    float s[4] = {0.f, 0.f, 0.f, 0.f};
#pragma unroll
    for (int it = 0; it < 3; it++) {
      int hh = it * 256 + lane * 4;
      f32x4 hv = *(f32x4*)&hw[hh];
      f32x4 vv = *(const f32x4*)&v[hh];
#pragma unroll
      for (int j = 0; j < 4; j++) {
        int r = rb + j * 4;
        if (r < NR) {
          f16x4 fv = *(const f16x4*)&fpb[(size_t)r * NH + hh];
#pragma unroll
          for (int q = 0; q < 4; q++) s[j] += fast_tanh((float)fv[q] + hv[q]) * vv[q];
        }
      }
    }
#pragma unroll
    for (int j = 0; j < 4; j++) {
      int r = rb + j * 4;
      if (r < NR) {
        float ss = s[j];
#pragma unroll
        for (int off = 32; off; off >>= 1) ss += __shfl_down(ss, off);
        if (lane == 0) sc[r] = ss;
      }
    }
  }
  __syncthreads();
  if (tid < 64) {
    float s = (tid < NR) ? sc[tid] : -1e30f;
    float m = s;
#pragma unroll
    for (int off = 32; off; off >>= 1) m = fmaxf(m, __shfl_xor(m, off));
    float e = (tid < NR) ? __expf(s - m) : 0.f;
    float su = e;
#pragma unroll
    for (int off = 32; off; off >>= 1) su += __shfl_xor(su, off);
    al[tid] = e / su;
  }
  __syncthreads();
#pragma unroll
  for (int j = 0; j < 3; j++) {
    int f = tid + j * 256;
    const _Float16* fb = feat16 + (size_t)b * NR * NH + f;
    float acc = 0.f;
#pragma unroll
    for (int r = 0; r < NR; r++) acc += al[r] * (float)fb[(size_t)r * NH];
    ctx16[(size_t)b * NH + f] = (_Float16)acc;
  }
}

// ---------------- g2 GEMM (BN=32, BK=128) + fused LSTM epilogue (192 blocks) ----------------
// C = ctx16 (128x768) @ Wc_int.T (3072x768), interleaved cols j' = 4*hh+gate.
__global__ __launch_bounds__(256) void k_g2lstm(
    const _Float16* __restrict__ A, const _Float16* __restrict__ Bt,
    const float* __restrict__ g1, const _Float16* __restrict__ ge_t,
    const float* __restrict__ bias_int, float* __restrict__ c, float* __restrict__ hf,
    _Float16* __restrict__ h16, _Float16* __restrict__ Hall_t) {
  constexpr int BK = 128;
  __shared__ __attribute__((aligned(16))) _Float16 sA[64 * BK];  // 16 KB
  __shared__ __attribute__((aligned(16))) _Float16 sB[32 * BK];  // 8 KB
  __shared__ float sC[64 * 36];                                  // 9 KB
  const int tid = threadIdx.x;
  const int m0 = blockIdx.x * 64, n0 = blockIdx.y * 32;
  const int wid = tid >> 6, lane = tid & 63;
  const int wr = wid >> 1, wc = wid & 1;
  const int lr = lane & 15, lk = (lane >> 4) * 8;

  f32x4 acc[2] = {};

  for (int kt = 0; kt < 6; ++kt) {
    const int kbase = kt * BK;
#pragma unroll
    for (int i = 0; i < 4; i++) {
      int idx = tid + i * 256;
      int row = idx >> 4, seg = idx & 15;
      gld16(A + (size_t)(m0 + row) * NH + kbase + seg * 8, sA + idx * 8);
    }
#pragma unroll
    for (int i = 0; i < 2; i++) {
      int idx = tid + i * 256;
      int row = idx >> 4, seg = idx & 15;
      gld16(Bt + (size_t)(n0 + row) * NH + kbase + seg * 8, sB + idx * 8);
    }
    __syncthreads();
#pragma unroll
    for (int kk = 0; kk < 4; ++kk) {
      f16x8 af0 = *(const f16x8*)&sA[(wr * 32 + lr) * BK + kk * 32 + lk];
      f16x8 af1 = *(const f16x8*)&sA[(wr * 32 + 16 + lr) * BK + kk * 32 + lk];
      f16x8 bf = *(const f16x8*)&sB[(wc * 16 + lr) * BK + kk * 32 + lk];
      acc[0] = __builtin_amdgcn_mfma_f32_16x16x32_f16(af0, bf, acc[0], 0, 0, 0);
      acc[1] = __builtin_amdgcn_mfma_f32_16x16x32_f16(af1, bf, acc[1], 0, 0, 0);
    }
    __syncthreads();
  }

  const int rowb = (lane >> 4) * 4;
  const int jl = wc * 16 + lr;
#pragma unroll
  for (int m = 0; m < 2; m++) {
    int bl = wr * 32 + m * 16 + rowb;
#pragma unroll
    for (int j = 0; j < 4; j++) sC[(bl + j) * 36 + jl] = acc[m][j];
  }
  __syncthreads();

  // LSTM: 64 b x 8 hh per block; thread -> b_l = tid&63, 2 hh's
  const int b_l = tid & 63, q = tid >> 6;
  const int b_g = m0 + b_l;
#pragma unroll
  for (int i = 0; i < 2; i++) {
    int hh_l = q * 2 + i;
    int hh_g = (n0 >> 2) + hh_l;
    f32x4 g = *(const f32x4*)&sC[b_l * 36 + 4 * hh_l];
    f32x4 p0 = *(const f32x4*)&g1[(size_t)b_g * 3840 + 768 + 4 * hh_g];
    f32x4 p1 = *(const f32x4*)&g1[(size_t)NB * 3840 + (size_t)b_g * 3840 + 768 + 4 * hh_g];
    f16x4 ge = *(const f16x4*)&ge_t[(size_t)b_g * 3072 + 4 * hh_g];
    f32x4 bi = *(const f32x4*)&bias_int[4 * hh_g];
    float gi = g[0] + p0[0] + p1[0] + (float)ge[0] + bi[0];
    float gf = g[1] + p0[1] + p1[1] + (float)ge[1] + bi[1];
    float gg = g[2] + p0[2] + p1[2] + (float)ge[2] + bi[2];
    float go = g[3] + p0[3] + p1[3] + (float)ge[3] + bi[3];
    float cn = sigm(gf) * c[b_g * NH + hh_g] + sigm(gi) * fast_tanh(gg);
    float hn = sigm(go) * fast_tanh(cn);
    c[b_g * NH + hh_g] = cn;
    hf[b_g * NH + hh_g] = hn;
    h16[(size_t)b_g * NH + hh_g] = (_Float16)hn;
    Hall_t[(size_t)b_g * NH + hh_g] = (_Float16)hn;
  }
}

// ---------------- prep kernels ----------------
__global__ void k_f32_to_f16(const float* __restrict__ src, _Float16* __restrict__ dst, int n) {
  int i = blockIdx.x * 256 + threadIdx.x;
  if (i < n) dst[i] = (_Float16)src[i];
}

// interleaved gate weights: j' = 4*hh + gate  (src row = gate*768 + hh)
__global__ void k_wint(const float* __restrict__ W_ih, const float* __restrict__ W_hh,
                       _Float16* __restrict__ We_int, _Float16* __restrict__ Wc_int,
                       _Float16* __restrict__ W1) {
  int jp = blockIdx.x;  // 0..3071
  int k = blockIdx.y * 256 + threadIdx.x;
  int src = (jp & 3) * NH + (jp >> 2);
  We_int[(size_t)jp * NH + k] = (_Float16)W_ih[(size_t)src * 1536 + k];
  Wc_int[(size_t)jp * NH + k] = (_Float16)W_ih[(size_t)src * 1536 + 768 + k];
  W1[(size_t)(768 + jp) * NH + k] = (_Float16)W_hh[(size_t)src * NH + k];
}

__global__ void k_wh(const float* __restrict__ attn_W, _Float16* __restrict__ W1) {
  int j = blockIdx.x;
  int k = blockIdx.y * 256 + threadIdx.x;
  W1[(size_t)j * NH + k] = (_Float16)attn_W[(size_t)j * 1536 + 768 + k];
}

__global__ void k_bias(const float* __restrict__ b_ih, const float* __restrict__ b_hh,
                       float* __restrict__ bias_int) {
  int jp = blockIdx.x * 256 + threadIdx.x;  // 3072
  int src = (jp & 3) * NH + (jp >> 2);
  bias_int[jp] = b_ih[src] + b_hh[src];
}

__global__ void k_emb2(const int* __restrict__ captions, const float* __restrict__ emb_W,
                       _Float16* __restrict__ emb16) {
  int row = blockIdx.x;  // t*128+b
  int k = blockIdx.y * 256 + threadIdx.x;
  int t = row >> 7, b = row & 127;
  int tok = captions[b * NT + t];
  emb16[(size_t)row * NH + k] = (_Float16)emb_W[(size_t)tok * NH + k];
}

__global__ void k_init(const float* __restrict__ features, float* __restrict__ c,
                       _Float16* __restrict__ h16) {
  int b = blockIdx.x;
  int f = blockIdx.y * 256 + threadIdx.x;
  float s = 0.f;
#pragma unroll 7
  for (int r = 0; r < NR; r++) s += features[((size_t)(b * NR + r)) * NH + f];
  float h0 = tanhf(s * (1.f / 49.f));
  c[b * NH + f] = 0.f;
  h16[(size_t)b * NH + f] = (_Float16)h0;
}

__global__ void k_tail(const float* __restrict__ h, const float* __restrict__ c,
                       float* __restrict__ out) {
  int i = blockIdx.x * 256 + threadIdx.x;  // 98304
  out[OUT_ELEMS + i] = h[i];
  out[OUT_ELEMS + NB * NH + i] = c[i];
}

// ---------------- host ----------------
extern "C" void kernel_launch(void* const* d_in, const int* in_sizes, int n_in,
                              void* d_out, int out_size, void* d_ws, size_t ws_size,
                              hipStream_t stream) {
  const float* features = (const float*)d_in[0];
  const int* captions = (const int*)d_in[1];
  const float* emb_W = (const float*)d_in[2];
  const float* attn_W = (const float*)d_in[3];
  const float* attn_b = (const float*)d_in[4];
  const float* attnv_W = (const float*)d_in[5];
  // d_in[6] attnv_b: constant shift, cancels in softmax
  const float* W_ih = (const float*)d_in[7];
  const float* W_hh = (const float*)d_in[8];
  const float* b_ih = (const float*)d_in[9];
  const float* b_hh = (const float*)d_in[10];
  const float* fc_W = (const float*)d_in[11];
  const float* fc_b = (const float*)d_in[12];
  float* out = (float*)d_out;

  char* p = (char*)d_ws;
  _Float16* Gemb16 = (_Float16*)p;  p += 25165824;  // (4096,3072) interleaved; aliased by fcW16
  _Float16* fcW16 = Gemb16;                         // (10000,768), reuse after scan
  _Float16* emb16 = (_Float16*)p;   p += 6291456;   // (4096,768): row t*128+b
  _Float16* feat16 = (_Float16*)p;  p += 9633792;   // (6272,768)
  _Float16* fp16 = (_Float16*)p;    p += 9633792;   // feat_proj + attn_b (6272,768)
  _Float16* attnW16 = (_Float16*)p; p += 2359296;   // (768,1536)
  _Float16* W1 = (_Float16*)p;      p += 5898240;   // (3840,768): [Wh ; Whh_int]
  _Float16* We_int = (_Float16*)p;  p += 4718592;   // (3072,768)
  _Float16* Wc_int = (_Float16*)p;  p += 4718592;   // (3072,768)
  _Float16* H_all = (_Float16*)p;   p += 6291456;   // (4096,768): row t*128+b
  float* g1 = (float*)p;            p += 3932160;   // 2 x (128,3840)
  float* bias_int = (float*)p;      p += 12288;     // (3072,)
  _Float16* ctx16 = (_Float16*)p;   p += 196608;    // (128,768)
  _Float16* h16 = (_Float16*)p;     p += 196608;    // (128,768)
  float* hbuf = (float*)p;          p += 393216;
  float* cbuf = (float*)p;          p += 393216;    // ~80 MB total

  // ---- phase A ----
  k_f32_to_f16<<<dim3(18816), 256, 0, stream>>>(features, feat16, 4816896);
  k_f32_to_f16<<<dim3(4608), 256, 0, stream>>>(attn_W, attnW16, 1179648);
  k_wint<<<dim3(3072, 3), 256, 0, stream>>>(W_ih, W_hh, We_int, Wc_int, W1);
  k_wh<<<dim3(768, 3), 256, 0, stream>>>(attn_W, W1);
  k_bias<<<dim3(12), 256, 0, stream>>>(b_ih, b_hh, bias_int);
  k_emb2<<<dim3(4096, 3), 256, 0, stream>>>(captions, emb_W, emb16);
  k_init<<<dim3(128, 3), 256, 0, stream>>>(features, cbuf, h16);
  // fp16 = features @ Wf.T + attn_b   (6272x768, K=768)
  gemm_f16<128, 128, 3, 64><<<dim3(49, 6), 256, 0, stream>>>(
      feat16, 768, attnW16, 1536, fp16, attn_b, 6272, 768, 12, 0);
  // Gemb = emb @ We_int.T  (4096x3072, K=768), f16, interleaved cols
  gemm_f16<128, 128, 4, 64><<<dim3(32, 24), 256, 0, stream>>>(
      emb16, 768, We_int, 768, Gemb16, nullptr, 4096, 3072, 12, 0);

  // ---- sequential scan: 3 launches per step ----
  for (int t = 0; t < NT; t++) {
    // g1 = h @ [Wh ; Whh_int].T  (128x3840, K=768, split-K 2, BK=128, fp32 partials)
    gemm_f16<64, 64, 1, 128><<<dim3(2, 60, 2), 256, 0, stream>>>(
        h16, 768, W1, 768, g1, nullptr, 128, 3840, 3, 384);
    k_attn<<<dim3(128), 256, 0, stream>>>(fp16, g1, attnv_W, feat16, ctx16);
    k_g2lstm<<<dim3(2, 96), 256, 0, stream>>>(
        ctx16, Wc_int, g1, Gemb16 + (size_t)t * NB * 3072, bias_int, cbuf, hbuf, h16,
        H_all + (size_t)t * NB * NH);
  }

  // ---- fc (fcW16 aliases Gemb16, safe after scan in stream order) ----
  k_f32_to_f16<<<dim3(30000), 256, 0, stream>>>(fc_W, fcW16, 7680000);
  gemm_f16<128, 128, 2, 64><<<dim3(32, 79), 256, 0, stream>>>(
      H_all, 768, fcW16, 768, out, fc_b, 4096, 10000, 12, 0);
  k_tail<<<dim3(384), 256, 0, stream>>>(hbuf, cbuf, out);
}

// Round 7
// 1109.701 us; speedup vs baseline: 10.3818x; 1.5742x over previous
//
#include <hip/hip_runtime.h>

// SpatialAttentionLSTMDecoder on MI355X (gfx950). B=128,T=32,V=10000,F=H=768,R=49.
// R7: R2's proven 5-kernel loop (27.7 us/step) + R6's LDS-staged fc epilogue
// (adjacency-safe) + phase-A prep merged into one kernel (9->4 launches).
// Fused-step variants (R3/R6) measured slower; persistent grid (R5) much slower.

typedef _Float16 f16x8 __attribute__((ext_vector_type(8)));
typedef _Float16 f16x4 __attribute__((ext_vector_type(4)));
typedef float f32x4 __attribute__((ext_vector_type(4)));

#define NB 128
#define NT 32
#define NV 10000
#define NH 768
#define NR 49
#define OUT_ELEMS 40960000  // B*T*V

__device__ __forceinline__ float fast_tanh(float x) {
  x = fminf(9.f, fmaxf(-9.f, x));
  float e = __expf(2.f * x);
  return (e - 1.f) / (e + 1.f);
}
__device__ __forceinline__ float sigm(float x) { return 1.f / (1.f + __expf(-x)); }

__device__ __forceinline__ void gld16(const void* g, void* l) {
  __builtin_amdgcn_global_load_lds((const __attribute__((address_space(1))) void*)g,
                                   (__attribute__((address_space(3))) void*)l, 16, 0, 0);
}

// ---------------- generic f16 MFMA GEMM (16x16x32) ----------------
// C[m][n] = sum_k A[m][k]*Bt[n][k]. A: MxK lda, Bt: NxK ldb (both f16 row-major).
// EPI 1: f32 partials, C += z*M*N.
// EPI 2: fc epilogue: LDS-staged float4 stores, (b,t) remap, +bias, n<N guard.
// EPI 3: f16 out + bias.  EPI 4: f16 out plain.
template <int BM, int BN, int EPI>
__global__ __launch_bounds__(256) void gemm_f16(
    const _Float16* __restrict__ A, int lda,
    const _Float16* __restrict__ Bt, int ldb,
    void* __restrict__ Cv, const float* __restrict__ bias,
    int M, int N, int ksteps, int ksplit) {
  constexpr int BK = 64;
  // single allocation so the EPI2 epilogue can reuse the whole block safely
  __shared__ __attribute__((aligned(16))) _Float16 sAB[(BM + BN) * BK];
  _Float16* sA = sAB;
  _Float16* sB = sAB + BM * BK;
  const int tid = threadIdx.x;
  const int m0 = blockIdx.x * BM, n0 = blockIdx.y * BN;
  const int z = blockIdx.z;
  A += (size_t)z * ksplit;
  Bt += (size_t)z * ksplit;

  constexpr int WM = BM / 2, WN = BN / 2;
  constexpr int MF = WM / 16, NF = WN / 16;
  const int wid = tid >> 6, lane = tid & 63;
  const int wr = wid >> 1, wc = wid & 1;
  const int lr = lane & 15;
  const int lk = (lane >> 4) * 8;

  f32x4 acc[MF][NF] = {};

  for (int kt = 0; kt < ksteps; ++kt) {
    const int kbase = kt * BK;
#pragma unroll
    for (int i = 0; i < BM / 32; i++) {
      int idx = tid + i * 256;
      int row = idx >> 3, seg = idx & 7;
      gld16(A + (size_t)(m0 + row) * lda + kbase + seg * 8, sA + idx * 8);
    }
#pragma unroll
    for (int i = 0; i < BN / 32; i++) {
      int idx = tid + i * 256;
      int row = idx >> 3, seg = idx & 7;
      int gr = n0 + row;
      if (gr >= N) gr = N - 1;  // only possible for EPI==2 (N=10000)
      gld16(Bt + (size_t)gr * ldb + kbase + seg * 8, sB + idx * 8);
    }
    __syncthreads();
#pragma unroll
    for (int kk = 0; kk < 2; ++kk) {
      f16x8 af[MF], bf[NF];
#pragma unroll
      for (int m = 0; m < MF; m++)
        af[m] = *(const f16x8*)&sA[(wr * WM + m * 16 + lr) * BK + kk * 32 + lk];
#pragma unroll
      for (int n = 0; n < NF; n++)
        bf[n] = *(const f16x8*)&sB[(wc * WN + n * 16 + lr) * BK + kk * 32 + lk];
#pragma unroll
      for (int m = 0; m < MF; m++)
#pragma unroll
        for (int n = 0; n < NF; n++)
          acc[m][n] = __builtin_amdgcn_mfma_f32_16x16x32_f16(af[m], bf[n], acc[m][n], 0, 0, 0);
    }
    __syncthreads();
  }

  const int rowb = (lane >> 4) * 4;
  if (EPI == 2) {
    // LDS-staged epilogue: two 64-row halves, float4 coalesced stores.
    float* sC = (float*)sAB;  // 64*128*4 = 32 KB
#pragma unroll
    for (int h = 0; h < 2; h++) {
      if (wr == h) {
#pragma unroll
        for (int m = 0; m < MF; m++)
#pragma unroll
          for (int n = 0; n < NF; n++)
#pragma unroll
            for (int j = 0; j < 4; j++)
              sC[(m * 16 + rowb + j) * 128 + wc * 64 + n * 16 + lr] = acc[m][n][j];
      }
      __syncthreads();
#pragma unroll
      for (int i = 0; i < 8; i++) {
        int lrow = (tid >> 5) + i * 8;
        int col = (tid & 31) * 4;
        int gn = n0 + col;
        if (gn < N) {
          int r = m0 + h * 64 + lrow;
          int tt = r >> 7, b = r & 127;
          f32x4 val = *(f32x4*)&sC[lrow * 128 + col];
          f32x4 bb = *(const f32x4*)&bias[gn];
          val += bb;
          *(f32x4*)&((float*)Cv)[((size_t)(b * NT + tt)) * NV + gn] = val;
        }
      }
      __syncthreads();
    }
    return;
  }
#pragma unroll
  for (int m = 0; m < MF; m++) {
    int gm = m0 + wr * WM + m * 16 + rowb;
#pragma unroll
    for (int n = 0; n < NF; n++) {
      int gn = n0 + wc * WN + n * 16 + lr;
#pragma unroll
      for (int j = 0; j < 4; j++) {
        int r = gm + j;
        if (EPI == 1) {
          float* C = (float*)Cv + (size_t)z * M * N;
          C[(size_t)r * N + gn] = acc[m][n][j];
        } else if (EPI == 3) {
          ((_Float16*)Cv)[(size_t)r * N + gn] = (_Float16)(acc[m][n][j] + bias[gn]);
        } else {
          ((_Float16*)Cv)[(size_t)r * N + gn] = (_Float16)acc[m][n][j];
        }
      }
    }
  }
}

// ---------------- loop kernels (byte-identical to R2's proven set) ----------------
// scores[p] = v . tanh(fp[p,:] + hw[b,:]) , p = b*49+r, one wave per p
__global__ __launch_bounds__(256) void k_scores(
    const _Float16* __restrict__ fp, const float* __restrict__ g1,
    const float* __restrict__ v, float* __restrict__ sc) {
  int wid = threadIdx.x >> 6, lane = threadIdx.x & 63;
  int p = blockIdx.x * 4 + wid;  // 6272 = 1568 blocks * 4 waves
  int b = p / NR;
  const _Float16* fpr = fp + (size_t)p * NH;
  const float* hw0 = g1 + (size_t)b * 3840;
  const float* hw1 = g1 + (size_t)NB * 3840 + (size_t)b * 3840;
  float s = 0.f;
#pragma unroll
  for (int it = 0; it < 3; it++) {
    int h = it * 256 + lane * 4;
    f16x4 fv = *(const f16x4*)(fpr + h);
    f32x4 a0 = *(const f32x4*)(hw0 + h);
    f32x4 a1 = *(const f32x4*)(hw1 + h);
    f32x4 vv = *(const f32x4*)(v + h);
#pragma unroll
    for (int j = 0; j < 4; j++) s += fast_tanh((float)fv[j] + a0[j] + a1[j]) * vv[j];
  }
#pragma unroll
  for (int off = 32; off; off >>= 1) s += __shfl_down(s, off);
  if (lane == 0) sc[p] = s;
}

// softmax over r + context: ctx16[b, fchunk] ; grid (128, 3) x 256
__global__ __launch_bounds__(256) void k_ctx(const float* __restrict__ sc,
                                             const _Float16* __restrict__ feat16,
                                             _Float16* __restrict__ ctx16) {
  __shared__ float al[64];
  int b = blockIdx.x, tid = threadIdx.x;
  if (tid < 64) {
    float s = (tid < NR) ? sc[b * NR + tid] : -1e30f;
    float m = s;
#pragma unroll
    for (int off = 32; off; off >>= 1) m = fmaxf(m, __shfl_xor(m, off));
    float e = (tid < NR) ? __expf(s - m) : 0.f;
    float su = e;
#pragma unroll
    for (int off = 32; off; off >>= 1) su += __shfl_xor(su, off);
    al[tid] = e / su;
  }
  __syncthreads();
  int f = blockIdx.y * 256 + tid;
  const _Float16* fb = feat16 + (size_t)b * NR * NH + f;
  float acc = 0.f;
#pragma unroll
  for (int r = 0; r < NR; r++) acc += al[r] * (float)fb[(size_t)r * NH];
  ctx16[(size_t)b * NH + f] = (_Float16)acc;
}

// LSTM elementwise: gates = G_emb[t] + g1(h-part, 2 z) + g2(ctx-part, 2 z) + biases
__global__ void k_lstm2(const _Float16* __restrict__ ge_t, const float* __restrict__ g1,
                        const float* __restrict__ g2, const float* __restrict__ b_ih,
                        const float* __restrict__ b_hh, float* __restrict__ h,
                        float* __restrict__ c, _Float16* __restrict__ h16,
                        _Float16* __restrict__ Hall_t) {
  int b = blockIdx.x;
  int hh = blockIdx.y * 256 + threadIdx.x;
  const _Float16* ge = ge_t + (size_t)b * 3072;
  const float* a0 = g1 + (size_t)b * 3840 + 768;
  const float* a1 = g1 + (size_t)NB * 3840 + (size_t)b * 3840 + 768;
  const float* c0 = g2 + (size_t)b * 3072;
  const float* c1 = g2 + (size_t)NB * 3072 + (size_t)b * 3072;
  float gi = (float)ge[hh] + a0[hh] + a1[hh] + c0[hh] + c1[hh] + b_ih[hh] + b_hh[hh];
  float gf = (float)ge[768 + hh] + a0[768 + hh] + a1[768 + hh] + c0[768 + hh] + c1[768 + hh] +
             b_ih[768 + hh] + b_hh[768 + hh];
  float gg = (float)ge[1536 + hh] + a0[1536 + hh] + a1[1536 + hh] + c0[1536 + hh] +
             c1[1536 + hh] + b_ih[1536 + hh] + b_hh[1536 + hh];
  float go = (float)ge[2304 + hh] + a0[2304 + hh] + a1[2304 + hh] + c0[2304 + hh] +
             c1[2304 + hh] + b_ih[2304 + hh] + b_hh[2304 + hh];
  float i_ = sigm(gi), f_ = sigm(gf), g_ = fast_tanh(gg), o_ = sigm(go);
  float cn = f_ * c[b * NH + hh] + i_ * g_;
  float hn = o_ * fast_tanh(cn);
  c[b * NH + hh] = cn;
  h[b * NH + hh] = hn;
  h16[(size_t)b * NH + hh] = (_Float16)hn;
  Hall_t[(size_t)b * NH + hh] = (_Float16)hn;
}

// ---------------- phase-A prep: one kernel, block-range dispatch ----------------
// S0 feat16(4816896) | S1 Wf16(589824) | S2 W1(2949120) | S3 We(2359296) |
// S4 Wc(2359296) | S5 emb16(3145728).  Block counts: 18816|2304|11520|9216|9216|12288.
__global__ void k_prep(const float* __restrict__ features, const float* __restrict__ attn_W,
                       const float* __restrict__ W_ih, const float* __restrict__ W_hh,
                       const int* __restrict__ captions, const float* __restrict__ emb_W,
                       _Float16* __restrict__ feat16, _Float16* __restrict__ Wf16,
                       _Float16* __restrict__ W1, _Float16* __restrict__ We,
                       _Float16* __restrict__ Wc, _Float16* __restrict__ emb16) {
  const int blk = blockIdx.x, tid = threadIdx.x;
  if (blk < 18816) {
    int i = blk * 256 + tid;
    feat16[i] = (_Float16)features[i];
  } else if (blk < 21120) {
    int q = (blk - 18816) * 256 + tid;
    int j = q / NH, k = q - j * NH;
    Wf16[q] = (_Float16)attn_W[(size_t)j * 1536 + k];
  } else if (blk < 32640) {
    int q = (blk - 21120) * 256 + tid;
    int j = q / NH, k = q - j * NH;
    W1[q] = (_Float16)(j < NH ? attn_W[(size_t)j * 1536 + 768 + k]
                              : W_hh[(size_t)(j - NH) * NH + k]);
  } else if (blk < 41856) {
    int q = (blk - 32640) * 256 + tid;
    int j = q / NH, k = q - j * NH;
    We[q] = (_Float16)W_ih[(size_t)j * 1536 + k];
  } else if (blk < 51072) {
    int q = (blk - 41856) * 256 + tid;
    int j = q / NH, k = q - j * NH;
    Wc[q] = (_Float16)W_ih[(size_t)j * 1536 + 768 + k];
  } else {
    int q = (blk - 51072) * 256 + tid;
    int row = q / NH, k = q - row * NH;  // row = t*128+b
    int t = row >> 7, b = row & 127;
    int tok = captions[b * NT + t];
    emb16[q] = (_Float16)emb_W[(size_t)tok * NH + k];
  }
}

__global__ void k_f32_to_f16(const float* __restrict__ src, _Float16* __restrict__ dst, int n) {
  int i = blockIdx.x * 256 + threadIdx.x;
  if (i < n) dst[i] = (_Float16)src[i];
}

// h0 = tanh(mean_r features), c0 = 0
__global__ void k_init(const float* __restrict__ features, float* __restrict__ h,
                       float* __restrict__ c, _Float16* __restrict__ h16) {
  int b = blockIdx.x;
  int f = blockIdx.y * 256 + threadIdx.x;
  float s = 0.f;
#pragma unroll 7
  for (int r = 0; r < NR; r++) s += features[((size_t)(b * NR + r)) * NH + f];
  float h0 = tanhf(s * (1.f / 49.f));
  h[b * NH + f] = h0;
  c[b * NH + f] = 0.f;
  h16[(size_t)b * NH + f] = (_Float16)h0;
}

__global__ void k_tail(const float* __restrict__ h, const float* __restrict__ c,
                       float* __restrict__ out) {
  int i = blockIdx.x * 256 + threadIdx.x;  // 98304
  out[OUT_ELEMS + i] = h[i];
  out[OUT_ELEMS + NB * NH + i] = c[i];
}

// ---------------- host ----------------
extern "C" void kernel_launch(void* const* d_in, const int* in_sizes, int n_in,
                              void* d_out, int out_size, void* d_ws, size_t ws_size,
                              hipStream_t stream) {
  const float* features = (const float*)d_in[0];
  const int* captions = (const int*)d_in[1];
  const float* emb_W = (const float*)d_in[2];
  const float* attn_W = (const float*)d_in[3];
  const float* attn_b = (const float*)d_in[4];
  const float* attnv_W = (const float*)d_in[5];
  // d_in[6] attnv_b: constant shift, cancels in softmax
  const float* W_ih = (const float*)d_in[7];
  const float* W_hh = (const float*)d_in[8];
  const float* b_ih = (const float*)d_in[9];
  const float* b_hh = (const float*)d_in[10];
  const float* fc_W = (const float*)d_in[11];
  const float* fc_b = (const float*)d_in[12];
  float* out = (float*)d_out;

  char* p = (char*)d_ws;
  _Float16* Gemb16 = (_Float16*)p;  p += 25165824;  // (4096,3072); aliased by fcW16 after loop
  _Float16* fcW16 = Gemb16;                         // (10000,768), reuse after loop
  _Float16* emb16 = (_Float16*)p;   p += 6291456;   // (4096,768): row t*128+b
  _Float16* feat16 = (_Float16*)p;  p += 9633792;   // (6272,768)
  _Float16* fp16 = (_Float16*)p;    p += 9633792;   // feat_proj + attn_b (6272,768)
  _Float16* Wf16 = (_Float16*)p;    p += 1179648;   // (768,768)
  _Float16* W1 = (_Float16*)p;      p += 5898240;   // (3840,768): [Wh ; W_hh]
  _Float16* We16 = (_Float16*)p;    p += 4718592;   // (3072,768)
  _Float16* Wc16 = (_Float16*)p;    p += 4718592;   // (3072,768)
  _Float16* H_all = (_Float16*)p;   p += 6291456;   // (4096,768): row t*128+b
  float* g1 = (float*)p;            p += 3932160;   // 2 x (128,3840)
  float* g2 = (float*)p;            p += 3145728;   // 2 x (128,3072)
  float* scores = (float*)p;        p += 25088;     // (6272,)
  _Float16* ctx16 = (_Float16*)p;   p += 196608;    // (128,768)
  _Float16* h16 = (_Float16*)p;     p += 196608;    // (128,768)
  float* hbuf = (float*)p;          p += 393216;
  float* cbuf = (float*)p;          p += 393216;    // ~82 MB total

  // ---- phase A: 4 launches ----
  k_prep<<<dim3(63360), 256, 0, stream>>>(features, attn_W, W_ih, W_hh, captions, emb_W,
                                          feat16, Wf16, W1, We16, Wc16, emb16);
  k_init<<<dim3(128, 3), 256, 0, stream>>>(features, hbuf, cbuf, h16);
  // fp16 = features @ Wf.T + attn_b   (6272x768, K=768)
  gemm_f16<128, 128, 3><<<dim3(49, 6, 1), 256, 0, stream>>>(
      feat16, 768, Wf16, 768, fp16, attn_b, 6272, 768, 12, 0);
  // Gemb = emb @ We.T  (4096x3072, K=768), f16 out
  gemm_f16<128, 128, 4><<<dim3(32, 24, 1), 256, 0, stream>>>(
      emb16, 768, We16, 768, Gemb16, nullptr, 4096, 3072, 12, 0);

  // ---- sequential scan: R2's proven 5-kernel step ----
  for (int t = 0; t < NT; t++) {
    if (t > 0)
      k_lstm2<<<dim3(128, 3), 256, 0, stream>>>(
          Gemb16 + (size_t)(t - 1) * NB * 3072, g1, g2, b_ih, b_hh, hbuf, cbuf, h16,
          H_all + (size_t)(t - 1) * NB * NH);
    // g1 = h @ [Wh ; W_hh].T  (128x3840, K=768, split-K 2)
    gemm_f16<64, 64, 1><<<dim3(2, 60, 2), 256, 0, stream>>>(
        h16, 768, W1, 768, g1, nullptr, 128, 3840, 6, 384);
    k_scores<<<dim3(1568), 256, 0, stream>>>(fp16, g1, attnv_W, scores);
    k_ctx<<<dim3(128, 3), 256, 0, stream>>>(scores, feat16, ctx16);
    // g2 = ctx @ Wc.T  (128x3072, K=768, split-K 2)
    gemm_f16<64, 64, 1><<<dim3(2, 48, 2), 256, 0, stream>>>(
        ctx16, 768, Wc16, 768, g2, nullptr, 128, 3072, 6, 384);
  }
  k_lstm2<<<dim3(128, 3), 256, 0, stream>>>(
      Gemb16 + (size_t)(NT - 1) * NB * 3072, g1, g2, b_ih, b_hh, hbuf, cbuf, h16,
      H_all + (size_t)(NT - 1) * NB * NH);

  // ---- fc (fcW16 aliases Gemb16, safe after last lstm in stream order) ----
  k_f32_to_f16<<<dim3(30000), 256, 0, stream>>>(fc_W, fcW16, 7680000);
  gemm_f16<128, 128, 2><<<dim3(32, 79, 1), 256, 0, stream>>>(
      H_all, 768, fcW16, 768, out, fc_b, 4096, 10000, 12, 0);
  k_tail<<<dim3(384), 256, 0, stream>>>(hbuf, cbuf, out);
}